// Round 10
// baseline (261.555 us; speedup 1.0000x reference)
//
#include <hip/hip_runtime.h>

// ---------------- constants (B=8,S=8192 -> N=65536, D=512, E=209) ------------
#define DK 512         // feature dim
#define TPW 16         // tokens per wave
#define NSTEP 16       // K steps of 32
#define NPANEL 14      // expert panels of 16 -> EPAD
#define EPAD 224
#define WFRAG_ELEMS (EPAD * DK)   // 114688 bf16 per array

typedef __attribute__((ext_vector_type(8))) short bf16x8;   // 8 bf16 = 4 VGPR
typedef __attribute__((ext_vector_type(4))) float f32x4;

__device__ __forceinline__ unsigned short f2b(float f) {   // f32 -> bf16 RNE
    unsigned u = __float_as_uint(f);
    return (unsigned short)((u + 0x7fffu + ((u >> 16) & 1u)) >> 16);
}
__device__ __forceinline__ float b2f(unsigned short h) {
    return __uint_as_float((unsigned)h << 16);
}
// RNE split (prep only)
__device__ __forceinline__ void split4(float4 v, ushort4& h, ushort4& lo) {
    h.x = f2b(v.x); h.y = f2b(v.y); h.z = f2b(v.z); h.w = f2b(v.w);
    lo.x = f2b(v.x - b2f(h.x)); lo.y = f2b(v.y - b2f(h.y));
    lo.z = f2b(v.z - b2f(h.z)); lo.w = f2b(v.w - b2f(h.w));
}
// 8 consecutive f32 -> hi (trunc) + lo (RNE of residual) bf16x8
__device__ __forceinline__ void pack8(float4 a, float4 b, bf16x8& h, bf16x8& lo) {
    float v[8] = {a.x, a.y, a.z, a.w, b.x, b.y, b.z, b.w};
    #pragma unroll
    for (int j = 0; j < 8; ++j) {
        unsigned u = __float_as_uint(v[j]);
        h[j]  = (short)(u >> 16);
        lo[j] = (short)f2b(v[j] - __uint_as_float(u & 0xffff0000u));
    }
}

// ---------------------------------------------------------------- init -------
extern "C" __global__ void moe_init(float* hist, float* probsum, int* cnt) {
    int t = threadIdx.x;
    if (t < EPAD) { hist[t] = 0.f; probsum[t] = 0.f; }
    if (t == 0) *cnt = 0;
}

// ---------------------------------------------------------------- prep -------
// One-time: w [E][DK] f32 -> fragment-major bf16 hi/lo arrays.
// idx = ((kk*14+p)*64 + l)*8 + j  holds  w[p*16+(l&15)][kk*32+(l>>4)*8+j].
extern "C" __global__ void __launch_bounds__(256)
moe_prep(const float* __restrict__ w,
         unsigned short* __restrict__ wHi,
         unsigned short* __restrict__ wLo, int E)
{
    int g = blockIdx.x * 256 + threadIdx.x;      // 0..14335
    int l  = g & 63;
    int pc = g >> 6;                              // kk*14 + p
    int kk = pc / NPANEL;
    int p  = pc - kk * NPANEL;
    int e  = p * 16 + (l & 15);
    int k0 = kk * 32 + (l >> 4) * 8;
    float4 v0 = make_float4(0.f,0.f,0.f,0.f), v1 = v0;
    if (e < E) {
        v0 = *(const float4*)(w + (size_t)e * DK + k0);
        v1 = *(const float4*)(w + (size_t)e * DK + k0 + 4);
    }
    ushort4 h0, l0, h1, l1;
    split4(v0, h0, l0); split4(v1, h1, l1);
    size_t off = (size_t)g * 8;
    *(ushort4*)(wHi + off)     = h0;
    *(ushort4*)(wHi + off + 4) = h1;
    *(ushort4*)(wLo + off)     = l0;
    *(ushort4*)(wLo + off + 4) = l1;
}

// ---------------------------------------------------------------- copy -------
// Standalone coalesced x -> out copy (x_flat). Keeps stores OUT of the GEMM
// loop (in-order vmcnt: a store ahead of a load forces load-waits to drain it).
extern "C" __global__ void __launch_bounds__(256)
moe_copy(const float4* __restrict__ xin, float4* __restrict__ outv, int n4)
{
    int i = blockIdx.x * 256 + threadIdx.x;
    int stride = gridDim.x * 256;
    for (; i < n4; i += stride) outv[i] = xin[i];
}

// ---------------------------------------------------------------- gemm -------
// Latency-hiding shape: wave = 16 tokens x 224 experts, acc = 14 f32x4
// (56 AGPR, ~146 regs total) -> 4096 waves = 4/SIMD = 16 waves/CU.
// No stores, no LDS, no barriers in the K loop. A frags direct from global
// (lane l: row tok0+(l&15), k (l>>4)*8), split in-register; B frags from
// fragment-major wHi/wLo. Softmax fully in-register (16-lane butterflies).
extern "C" __global__ void __launch_bounds__(256, 4)
moe_gemm(const float* __restrict__ x,
         const unsigned short* __restrict__ wHi,
         const unsigned short* __restrict__ wLo,
         float* __restrict__ out,
         float* __restrict__ hist,
         float* __restrict__ probsum_g,
         int* __restrict__ flag_cnt,
         int* __restrict__ flag_list,
         int flag_cap, int N, int E)
{
    __shared__ float ps_l[EPAD];

    const int t  = threadIdx.x;
    const int l  = t & 63;
    const int wm = t >> 6;
    const int le = l & 15;                 // token row / expert-in-panel
    const int lg = l >> 4;                 // k-slice group / row group
    const int tok0 = blockIdx.x * 64 + wm * TPW;

    if (t < EPAD) ps_l[t] = 0.f;
    __syncthreads();                       // ps_l ready before epilogue atomics

    const float* xr = x + (size_t)(tok0 + le) * DK + lg * 8;

    f32x4 acc[NPANEL];
    #pragma unroll
    for (int pp = 0; pp < NPANEL; ++pp)
        acc[pp] = (f32x4){0.f, 0.f, 0.f, 0.f};

    #pragma unroll 2
    for (int kk = 0; kk < NSTEP; ++kk) {
        float4 a0 = *(const float4*)(xr + kk * 32);
        float4 a1 = *(const float4*)(xr + kk * 32 + 4);
        bf16x8 ah, al;
        pack8(a0, a1, ah, al);
        #pragma unroll
        for (int pp = 0; pp < NPANEL; ++pp) {
            size_t boff = ((size_t)(kk * NPANEL + pp) * 64 + l) * 8;
            bf16x8 bh = *(const bf16x8*)(wHi + boff);
            bf16x8 bl = *(const bf16x8*)(wLo + boff);
            acc[pp] = __builtin_amdgcn_mfma_f32_16x16x32_bf16(ah, bh, acc[pp], 0, 0, 0);
            acc[pp] = __builtin_amdgcn_mfma_f32_16x16x32_bf16(ah, bl, acc[pp], 0, 0, 0);
            acc[pp] = __builtin_amdgcn_mfma_f32_16x16x32_bf16(al, bh, acc[pp], 0, 0, 0);
        }
    }

    // -------- softmax in-register: C layout col=le (expert), row=lg*4+rg ----
    float m1r[4], svr[4];
    #pragma unroll
    for (int rg = 0; rg < 4; ++rg) {
        float m1 = -1e30f, m2 = -1e30f; int i1 = 0x7fff;
        #pragma unroll
        for (int pp = 0; pp < NPANEL; ++pp) {
            int e = pp * 16 + le;
            float v = (e < E) ? acc[pp][rg] : -1e30f;
            if (v > m1) { m2 = m1; m1 = v; i1 = e; }
            else if (v > m2) { m2 = v; }
        }
        #pragma unroll
        for (int mask = 1; mask < 16; mask <<= 1) {       // reduce over experts
            float om1 = __shfl_xor(m1, mask);
            float om2 = __shfl_xor(m2, mask);
            int   oi1 = __shfl_xor(i1, mask);
            if (om1 > m1 || (om1 == m1 && oi1 < i1)) {
                m2 = fmaxf(m1, om2); m1 = om1; i1 = oi1;
            } else {
                m2 = fmaxf(m2, om1);
            }
        }
        float s = 0.f;
        #pragma unroll
        for (int pp = 0; pp < NPANEL; ++pp) {
            int e = pp * 16 + le;
            float v = (e < E) ? acc[pp][rg] : -1e30f;
            s += __expf(v - m1);                          // invalid -> 0
        }
        #pragma unroll
        for (int mask = 1; mask < 16; mask <<= 1) s += __shfl_xor(s, mask);
        float sinv = 1.0f / s;
        m1r[rg] = m1; svr[rg] = sinv;
        if (le == 0) {                                    // writer lane
            int tok = tok0 + lg * 4 + rg;
            out[(size_t)N * DK + tok]     = sinv;         // max prob
            out[(size_t)N * DK + N + tok] = (float)i1;    // expert index
            atomicAdd(&hist[i1], 1.0f);
            if (m1 - m2 < 2e-4f) {                        // ambiguous argmax
                int pos = atomicAdd(flag_cnt, 1);
                if (pos < flag_cap) flag_list[pos] = tok;
            }
        }
    }

    // -------- per-expert prob sums: rows in-reg, groups via lanes 16/32 -----
    #pragma unroll
    for (int pp = 0; pp < NPANEL; ++pp) {
        int e = pp * 16 + le;
        float sum = 0.f;
        #pragma unroll
        for (int rg = 0; rg < 4; ++rg) {
            float v = (e < E) ? acc[pp][rg] : -1e30f;
            sum += __expf(v - m1r[rg]) * svr[rg];
        }
        sum += __shfl_xor(sum, 16);
        sum += __shfl_xor(sum, 32);
        if (lg == 0 && e < E) atomicAdd(&ps_l[e], sum);
    }
    __syncthreads();
    if (t < E) atomicAdd(&probsum_g[t], ps_l[t]);
}

// ------------------------------------------------------------- refine --------
// f64 recompute (original f32 w) for tokens with f32 top-2 gap < tau.
extern "C" __global__ void __launch_bounds__(256)
moe_refine(const float* __restrict__ x,
           const float* __restrict__ w,
           float* __restrict__ hist,
           const int* __restrict__ flag_cnt,
           const int* __restrict__ flag_list,
           int flag_cap,
           float* __restrict__ out,
           int N, int E)
{
    __shared__ float  xsh[DK];
    __shared__ double rv[256];
    __shared__ int    ri[256];
    int nf = *flag_cnt; if (nf > flag_cap) nf = flag_cap;
    const int tid = threadIdx.x;

    for (int li = blockIdx.x; li < nf; li += gridDim.x) {
        int tok = flag_list[li];
        for (int k = tid; k < DK; k += 256) xsh[k] = x[(size_t)tok * DK + k];
        __syncthreads();
        double a = -1e300;
        if (tid < E) {
            const float* wr = w + (size_t)tid * DK;
            double a0 = 0, a1 = 0, a2 = 0, a3 = 0;
            for (int k = 0; k < DK; k += 4) {
                a0 += (double)xsh[k]     * (double)wr[k];
                a1 += (double)xsh[k + 1] * (double)wr[k + 1];
                a2 += (double)xsh[k + 2] * (double)wr[k + 2];
                a3 += (double)xsh[k + 3] * (double)wr[k + 3];
            }
            a = (a0 + a1) + (a2 + a3);
        }
        rv[tid] = a; ri[tid] = tid;
        __syncthreads();
        for (int s = 128; s > 0; s >>= 1) {
            if (tid < s) {
                double vb = rv[tid + s]; int ib = ri[tid + s];
                double va = rv[tid];     int ia = ri[tid];
                if (vb > va || (vb == va && ib < ia)) { rv[tid] = vb; ri[tid] = ib; }
            }
            __syncthreads();
        }
        if (tid == 0) {
            int newi = ri[0];
            int oldi = (int)out[(size_t)N * DK + N + tok];
            if (newi != oldi) {
                atomicAdd(&hist[oldi], -1.0f);
                atomicAdd(&hist[newi],  1.0f);
                out[(size_t)N * DK + N + tok] = (float)newi;
            }
        }
        __syncthreads();
    }
}

// ------------------------------------------------------------ finalize -------
extern "C" __global__ void __launch_bounds__(256)
moe_final(const float* __restrict__ hist,
          const float* __restrict__ probsum,
          const float* __restrict__ ec_in,
          const float* __restrict__ gps_in,
          float* __restrict__ out,
          int N, int E)
{
    __shared__ double red[256];
    int t = threadIdx.x;
    double p = 0.0;
    if (t < E) p = (double)hist[t] * (double)probsum[t];
    red[t] = p;
    __syncthreads();
    for (int s = 128; s > 0; s >>= 1) {
        if (t < s) red[t] += red[t + s];
        __syncthreads();
    }
    size_t base = (size_t)N * DK + 2 * (size_t)N;
    if (t == 0) {
        double loss = (double)E * red[0] / ((double)N * (double)N);
        out[base] = (float)loss;
    }
    if (t < E) {
        out[base + 1 + t]     = 0.9f * ec_in[t]  + 0.1f * hist[t];
        out[base + 1 + E + t] = 0.9f * gps_in[t] + 0.1f * probsum[t];
    }
}

// ------------------------------------------------------------- launch --------
extern "C" void kernel_launch(void* const* d_in, const int* in_sizes, int n_in,
                              void* d_out, int out_size, void* d_ws, size_t ws_size,
                              hipStream_t stream)
{
    const float* x   = (const float*)d_in[0];
    const float* w   = (const float*)d_in[1];
    const float* ec  = (const float*)d_in[2];
    const float* gps = (const float*)d_in[3];
    float* out = (float*)d_out;

    int E = in_sizes[2];              // 209
    int N = in_sizes[0] / DK;         // 65536

    unsigned short* wHi = (unsigned short*)d_ws;
    unsigned short* wLo = wHi + WFRAG_ELEMS;
    float* hist    = (float*)(wLo + WFRAG_ELEMS);
    float* probsum = hist + EPAD;
    int*   cnt     = (int*)(probsum + EPAD);
    int*   list    = cnt + 1;
    long long used = 2LL * WFRAG_ELEMS * 2 + 4LL * (2 * EPAD + 1);
    long long cap_ll = ((long long)ws_size - used) / 4;
    int cap = cap_ll < 0 ? 0 : (cap_ll > 65536 ? 65536 : (int)cap_ll);

    int n4 = (N * DK) / 4;

    moe_prep  <<<56,     256, 0, stream>>>(w, wHi, wLo, E);
    moe_init  <<<1,      256, 0, stream>>>(hist, probsum, cnt);
    moe_gemm  <<<N / 64, 256, 0, stream>>>(x, wHi, wLo, out, hist, probsum, cnt, list, cap, N, E);
    moe_copy  <<<2048,   256, 0, stream>>>((const float4*)x, (float4*)out, n4);
    moe_refine<<<256,    256, 0, stream>>>(x, w, hist, cnt, list, cap, out, N, E);
    moe_final <<<1,      256, 0, stream>>>(hist, probsum, ec, gps, out, N, E);
}

// Round 11
// 201.045 us; speedup vs baseline: 1.3010x; 1.3010x over previous
//
#include <hip/hip_runtime.h>

// ---------------- constants (B=8,S=8192 -> N=65536, D=512, E=209) ------------
#define DK 512
#define NSTEP 16            // K steps of 32
#define NPANEL 14           // expert panels of 16 -> EPAD
#define EPAD 224
#define LP 225              // logits row stride (f32), phase 2
#define WFRAG_ELEMS (EPAD * DK)     // 114688 bf16 per array
#define STEPB 14336         // bytes per (step x 14 panels) frag block (hi or lo)

typedef __attribute__((ext_vector_type(8))) short bf16x8;
typedef __attribute__((ext_vector_type(4))) float f32x4;

__device__ __forceinline__ unsigned short f2b(float f) {   // f32 -> bf16 RNE
    unsigned u = __float_as_uint(f);
    return (unsigned short)((u + 0x7fffu + ((u >> 16) & 1u)) >> 16);
}
__device__ __forceinline__ float b2f(unsigned short h) {
    return __uint_as_float((unsigned)h << 16);
}
__device__ __forceinline__ void split4(float4 v, ushort4& h, ushort4& lo) {
    h.x = f2b(v.x); h.y = f2b(v.y); h.z = f2b(v.z); h.w = f2b(v.w);
    lo.x = f2b(v.x - b2f(h.x)); lo.y = f2b(v.y - b2f(h.y));
    lo.z = f2b(v.z - b2f(h.z)); lo.w = f2b(v.w - b2f(h.w));
}
// 8 consecutive f32 -> hi (trunc, residual exact) + lo (RNE) bf16x8
__device__ __forceinline__ void pack8(float4 a, float4 b, bf16x8& h, bf16x8& lo) {
    float v[8] = {a.x, a.y, a.z, a.w, b.x, b.y, b.z, b.w};
    #pragma unroll
    for (int j = 0; j < 8; ++j) {
        unsigned u = __float_as_uint(v[j]);
        h[j]  = (short)(u >> 16);
        lo[j] = (short)f2b(v[j] - __uint_as_float(u & 0xffff0000u));
    }
}
// async global->LDS, 16 B per lane. LDS dest wave-uniform; global src per-lane.
__device__ __forceinline__ void gld16(const void* g, void* l) {
    __builtin_amdgcn_global_load_lds(
        (const __attribute__((address_space(1))) unsigned int*)g,
        (__attribute__((address_space(3))) unsigned int*)l, 16, 0, 0);
}

// ---------------------------------------------------------------- init -------
extern "C" __global__ void moe_init(float* hist, float* probsum, int* cnt) {
    int t = threadIdx.x;
    if (t < EPAD) { hist[t] = 0.f; probsum[t] = 0.f; }
    if (t == 0) *cnt = 0;
}

// ---------------------------------------------------------------- prep -------
// w [E][DK] f32 -> fragment-major bf16 hi/lo arrays (bit-exact copy source for
// LDS staging). idx = ((kk*14+p)*64+l)*8+j  holds  w[p*16+(l&15)][kk*32+(l>>4)*8+j].
extern "C" __global__ void __launch_bounds__(256)
moe_prep(const float* __restrict__ w,
         unsigned short* __restrict__ wHi,
         unsigned short* __restrict__ wLo, int E)
{
    int g = blockIdx.x * 256 + threadIdx.x;      // 0..14335
    int l  = g & 63;
    int pc = g >> 6;
    int kk = pc / NPANEL;
    int p  = pc - kk * NPANEL;
    int e  = p * 16 + (l & 15);
    int k0 = kk * 32 + (l >> 4) * 8;
    float4 v0 = make_float4(0.f,0.f,0.f,0.f), v1 = v0;
    if (e < E) {
        v0 = *(const float4*)(w + (size_t)e * DK + k0);
        v1 = *(const float4*)(w + (size_t)e * DK + k0 + 4);
    }
    ushort4 h0, l0, h1, l1;
    split4(v0, h0, l0); split4(v1, h1, l1);
    size_t off = (size_t)g * 8;
    *(ushort4*)(wHi + off)     = h0;
    *(ushort4*)(wHi + off + 4) = h1;
    *(ushort4*)(wLo + off)     = l0;
    *(ushort4*)(wLo + off + 4) = l1;
}

// ---------------------------------------------------------------- gemm -------
// 4 waves (2 token-halves x 2 panel-halves), 64 tokens/block.
// 2-phase K loop: stage B(kk+1) into LDS via global_load_lds (async DMA, no
// VGPR round-trip) BEFORE computing kk from LDS; ONE __syncthreads per step
// (its vmcnt(0) drain is hidden under the 42-MFMA + ds_read phase).
// A frags direct global->reg (x-tile read exactly once); wn==0 waves emit the
// f32 x_flat copy. Numerics identical to R5-R10 (absmax 6e-5).
extern "C" __global__ void __launch_bounds__(256, 2)
moe_gemm(const float* __restrict__ x,
         const unsigned short* __restrict__ wHi,
         const unsigned short* __restrict__ wLo,
         float* __restrict__ out,
         float* __restrict__ hist,
         float* __restrict__ probsum_g,
         int* __restrict__ flag_cnt,
         int* __restrict__ flag_list,
         int flag_cap, int N, int E)
{
    __shared__ char Bl[2][2 * STEPB];            // 57344 B: [hi 14336][lo 14336]
    __shared__ float ps_l[EPAD];
    __shared__ float tok_m[32], tok_s[32];

    const int t    = threadIdx.x;
    const int l    = t & 63;
    const int wid  = t >> 6;
    const int wm   = wid >> 1;                   // token half
    const int wn   = wid & 1;                    // panel half
    const int le   = l & 15;
    const int lg   = l >> 4;
    const int tok0 = blockIdx.x * 64;

    if (t < EPAD) ps_l[t] = 0.f;

    f32x4 acc[2][7];
    #pragma unroll
    for (int mi = 0; mi < 2; ++mi)
        #pragma unroll
        for (int j = 0; j < 7; ++j)
            acc[mi][j] = (f32x4){0.f, 0.f, 0.f, 0.f};

    // stage step kk's B block into buf: 7 chunks of 1KB per wave (wave-uniform
    // LDS dest, per-lane global src). Pure bit-copy, no conversion.
    #define STAGE_B(kk_, buf_)                                                  \
        {   _Pragma("unroll")                                                   \
            for (int i_ = 0; i_ < 7; ++i_) {                                    \
                int c_ = wid * 7 + i_;                                          \
                const char* src_ = (c_ < NPANEL)                                \
                    ? ((const char*)wHi + (kk_) * STEPB + c_ * 1024 + l * 16)   \
                    : ((const char*)wLo + (kk_) * STEPB + (c_ - NPANEL) * 1024 + l * 16); \
                gld16(src_, (buf_) + c_ * 1024);                                \
            }                                                                   \
        }

    float4 Areg[2][2][2];                        // [parity][mi][half]
    // ---- prologue: A(0) + stage B(0) ----
    #pragma unroll
    for (int mi = 0; mi < 2; ++mi) {
        const float* ar = x + (size_t)(tok0 + wm * 32 + mi * 16 + le) * DK + lg * 8;
        Areg[0][mi][0] = *(const float4*)(ar);
        Areg[0][mi][1] = *(const float4*)(ar + 4);
    }
    STAGE_B(0, Bl[0]);
    __syncthreads();                             // drain: B(0) in LDS, A(0) in regs

    #pragma unroll
    for (int kk = 0; kk < NSTEP; ++kk) {
        const int p = kk & 1;
        // 1) issue next step's A loads + B stage (consumed after the barrier)
        if (kk + 1 < NSTEP) {
            #pragma unroll
            for (int mi = 0; mi < 2; ++mi) {
                const float* ar = x + (size_t)(tok0 + wm * 32 + mi * 16 + le) * DK
                                + (kk + 1) * 32 + lg * 8;
                Areg[1 - p][mi][0] = *(const float4*)(ar);
                Areg[1 - p][mi][1] = *(const float4*)(ar + 4);
            }
            STAGE_B(kk + 1, Bl[1 - p]);
        }
        // 2) x_flat copy for step kk (wn==0 waves only; avoids dup stores)
        if (wn == 0) {
            #pragma unroll
            for (int mi = 0; mi < 2; ++mi) {
                float* ow = out + (size_t)(tok0 + wm * 32 + mi * 16 + le) * DK
                          + kk * 32 + lg * 8;
                *(float4*)ow       = Areg[p][mi][0];
                *(float4*)(ow + 4) = Areg[p][mi][1];
            }
        }
        // 3) compute step kk: A split in-reg, B from LDS, 42 MFMA
        bf16x8 ah[2], al[2];
        pack8(Areg[p][0][0], Areg[p][0][1], ah[0], al[0]);
        pack8(Areg[p][1][0], Areg[p][1][1], ah[1], al[1]);
        #pragma unroll
        for (int j = 0; j < 7; ++j) {
            int q = wn * 7 + j;
            bf16x8 bh = *(const bf16x8*)(&Bl[p][q * 1024 + l * 16]);
            bf16x8 bl = *(const bf16x8*)(&Bl[p][STEPB + q * 1024 + l * 16]);
            #pragma unroll
            for (int mi = 0; mi < 2; ++mi) {
                acc[mi][j] = __builtin_amdgcn_mfma_f32_16x16x32_bf16(ah[mi], bh, acc[mi][j], 0, 0, 0);
                acc[mi][j] = __builtin_amdgcn_mfma_f32_16x16x32_bf16(ah[mi], bl, acc[mi][j], 0, 0, 0);
                acc[mi][j] = __builtin_amdgcn_mfma_f32_16x16x32_bf16(al[mi], bh, acc[mi][j], 0, 0, 0);
            }
        }
        // 4) one barrier per step: reads of Bl[p] done everywhere; next stage
        //    (into Bl[1-p]) retired by the implicit vmcnt(0) drain.
        __syncthreads();
    }

    // -------- phase 2: two 32-token passes over LDS logits (R5-verified) ----
    float* logits = (float*)&Bl[0][0];           // 28.8 KB, aliases B buffers

    for (int pass = 0; pass < 2; ++pass) {
        __syncthreads();
        if (wm == pass) {
            #pragma unroll
            for (int mi = 0; mi < 2; ++mi)
                #pragma unroll
                for (int nj = 0; nj < 7; ++nj)
                    #pragma unroll
                    for (int rg = 0; rg < 4; ++rg) {
                        int rr = mi * 16 + (l >> 4) * 4 + rg;   // 0..31
                        int cc = wn * 112 + nj * 16 + (l & 15); // 0..223
                        logits[rr * LP + cc] = acc[mi][nj][rg];
                    }
        }
        __syncthreads();
        {   // 8 threads per token: top-2 + softmax denom
            int r = t >> 3, sub = t & 7;
            float m1 = -1e30f, m2 = -1e30f;
            int i1 = 0x7fffffff;
            for (int e = sub; e < E; e += 8) {
                float v = logits[r * LP + e];
                if (v > m1) { m2 = m1; m1 = v; i1 = e; }
                else if (v > m2) { m2 = v; }
            }
            #pragma unroll
            for (int mask = 1; mask < 8; mask <<= 1) {
                float om1 = __shfl_xor(m1, mask);
                float om2 = __shfl_xor(m2, mask);
                int   oi1 = __shfl_xor(i1, mask);
                if (om1 > m1 || (om1 == m1 && oi1 < i1)) {
                    m2 = fmaxf(m1, om2); m1 = om1; i1 = oi1;
                } else {
                    m2 = fmaxf(m2, om1);
                }
            }
            float s = 0.f;
            for (int e = sub; e < E; e += 8) s += __expf(logits[r * LP + e] - m1);
            #pragma unroll
            for (int mask = 1; mask < 8; mask <<= 1) s += __shfl_xor(s, mask);

            if (sub == 0) {
                float sinv = 1.0f / s;
                tok_m[r] = m1; tok_s[r] = sinv;
                int tok = tok0 + pass * 32 + r;
                out[(size_t)N * DK + tok]     = sinv;        // max prob
                out[(size_t)N * DK + N + tok] = (float)i1;   // expert index
                atomicAdd(&hist[i1], 1.0f);
                if (m1 - m2 < 2e-4f) {                       // ambiguous argmax
                    int pos = atomicAdd(flag_cnt, 1);
                    if (pos < flag_cap) flag_list[pos] = tok;
                }
            }
        }
        __syncthreads();
        if (t < E) {                             // thread = expert: no atomics
            float sum = 0.f;
            #pragma unroll 4
            for (int r = 0; r < 32; ++r)
                sum += __expf(logits[r * LP + t] - tok_m[r]) * tok_s[r];
            ps_l[t] += sum;
        }
    }
    __syncthreads();
    if (t < E) atomicAdd(&probsum_g[t], ps_l[t]);
    #undef STAGE_B
}

// ------------------------------------------------------------- refine --------
extern "C" __global__ void __launch_bounds__(256)
moe_refine(const float* __restrict__ x,
           const float* __restrict__ w,
           float* __restrict__ hist,
           const int* __restrict__ flag_cnt,
           const int* __restrict__ flag_list,
           int flag_cap,
           float* __restrict__ out,
           int N, int E)
{
    __shared__ float  xsh[DK];
    __shared__ double rv[256];
    __shared__ int    ri[256];
    int nf = *flag_cnt; if (nf > flag_cap) nf = flag_cap;
    const int tid = threadIdx.x;

    for (int li = blockIdx.x; li < nf; li += gridDim.x) {
        int tok = flag_list[li];
        for (int k = tid; k < DK; k += 256) xsh[k] = x[(size_t)tok * DK + k];
        __syncthreads();
        double a = -1e300;
        if (tid < E) {
            const float* wr = w + (size_t)tid * DK;
            double a0 = 0, a1 = 0, a2 = 0, a3 = 0;
            for (int k = 0; k < DK; k += 4) {
                a0 += (double)xsh[k]     * (double)wr[k];
                a1 += (double)xsh[k + 1] * (double)wr[k + 1];
                a2 += (double)xsh[k + 2] * (double)wr[k + 2];
                a3 += (double)xsh[k + 3] * (double)wr[k + 3];
            }
            a = (a0 + a1) + (a2 + a3);
        }
        rv[tid] = a; ri[tid] = tid;
        __syncthreads();
        for (int s = 128; s > 0; s >>= 1) {
            if (tid < s) {
                double vb = rv[tid + s]; int ib = ri[tid + s];
                double va = rv[tid];     int ia = ri[tid];
                if (vb > va || (vb == va && ib < ia)) { rv[tid] = vb; ri[tid] = ib; }
            }
            __syncthreads();
        }
        if (tid == 0) {
            int newi = ri[0];
            int oldi = (int)out[(size_t)N * DK + N + tok];
            if (newi != oldi) {
                atomicAdd(&hist[oldi], -1.0f);
                atomicAdd(&hist[newi],  1.0f);
                out[(size_t)N * DK + N + tok] = (float)newi;
            }
        }
        __syncthreads();
    }
}

// ------------------------------------------------------------ finalize -------
extern "C" __global__ void __launch_bounds__(256)
moe_final(const float* __restrict__ hist,
          const float* __restrict__ probsum,
          const float* __restrict__ ec_in,
          const float* __restrict__ gps_in,
          float* __restrict__ out,
          int N, int E)
{
    __shared__ double red[256];
    int t = threadIdx.x;
    double p = 0.0;
    if (t < E) p = (double)hist[t] * (double)probsum[t];
    red[t] = p;
    __syncthreads();
    for (int s = 128; s > 0; s >>= 1) {
        if (t < s) red[t] += red[t + s];
        __syncthreads();
    }
    size_t base = (size_t)N * DK + 2 * (size_t)N;
    if (t == 0) {
        double loss = (double)E * red[0] / ((double)N * (double)N);
        out[base] = (float)loss;
    }
    if (t < E) {
        out[base + 1 + t]     = 0.9f * ec_in[t]  + 0.1f * hist[t];
        out[base + 1 + E + t] = 0.9f * gps_in[t] + 0.1f * probsum[t];
    }
}

// ------------------------------------------------------------- launch --------
extern "C" void kernel_launch(void* const* d_in, const int* in_sizes, int n_in,
                              void* d_out, int out_size, void* d_ws, size_t ws_size,
                              hipStream_t stream)
{
    const float* x   = (const float*)d_in[0];
    const float* w   = (const float*)d_in[1];
    const float* ec  = (const float*)d_in[2];
    const float* gps = (const float*)d_in[3];
    float* out = (float*)d_out;

    int E = in_sizes[2];              // 209
    int N = in_sizes[0] / DK;         // 65536

    unsigned short* wHi = (unsigned short*)d_ws;
    unsigned short* wLo = wHi + WFRAG_ELEMS;
    float* hist    = (float*)(wLo + WFRAG_ELEMS);
    float* probsum = hist + EPAD;
    int*   cnt     = (int*)(probsum + EPAD);
    int*   list    = cnt + 1;
    long long used = 2LL * WFRAG_ELEMS * 2 + 4LL * (2 * EPAD + 1);
    long long cap_ll = ((long long)ws_size - used) / 4;
    int cap = cap_ll < 0 ? 0 : (cap_ll > 65536 ? 65536 : (int)cap_ll);

    moe_prep  <<<56,     256, 0, stream>>>(w, wHi, wLo, E);
    moe_init  <<<1,      256, 0, stream>>>(hist, probsum, cnt);
    moe_gemm  <<<N / 64, 256, 0, stream>>>(x, wHi, wLo, out, hist, probsum, cnt, list, cap, N, E);
    moe_refine<<<256,    256, 0, stream>>>(x, w, hist, cnt, list, cap, out, N, E);
    moe_final <<<1,      256, 0, stream>>>(hist, probsum, ec, gps, out, N, E);
}